// Round 2
// baseline (21705.347 us; speedup 1.0000x reference)
//
#include <hip/hip_runtime.h>

typedef __bf16 bf16;
typedef __bf16 bf16x4 __attribute__((ext_vector_type(4)));
typedef __bf16 bf16x8 __attribute__((ext_vector_type(8)));
typedef float f32x4 __attribute__((ext_vector_type(4)));
typedef unsigned int u32;

#define T_STEPS 1024
#define BATCH 128
#define DIM 256      // D
#define HID 512      // H
#define NB 64        // blocks; block owns 8 h-columns (32 gate rows)

__device__ __forceinline__ f32x4 mfma_bf16(bf16x8 a, bf16x8 b, f32x4 c) {
  return __builtin_amdgcn_mfma_f32_16x16x32_bf16(a, b, c, 0, 0, 0);
}
__device__ __forceinline__ float fast_sigmoid(float v) {
  return __builtin_amdgcn_rcpf(1.f + __expf(-v));
}
__device__ __forceinline__ float fast_tanh(float v) {
  return 2.f * __builtin_amdgcn_rcpf(1.f + __expf(-2.f * v)) - 1.f;
}
// load 8 consecutive f32, convert to bf16x8 fragment
__device__ __forceinline__ bf16x8 cvt8(const float* p) {
  float4 a = *(const float4*)p;
  float4 b = *(const float4*)(p + 4);
  bf16x8 r;
  r[0] = (bf16)a.x; r[1] = (bf16)a.y; r[2] = (bf16)a.z; r[3] = (bf16)a.w;
  r[4] = (bf16)b.x; r[5] = (bf16)b.y; r[6] = (bf16)b.z; r[7] = (bf16)b.w;
  return r;
}

// ws layout: [0..127] barrier (cnt, gen), [128 ..] hbuf[2][128*512] bf16
__global__ __launch_bounds__(256) void lstm_persist(
    const float* __restrict__ x, const float* __restrict__ Wx,
    const float* __restrict__ bx, const float* __restrict__ Wh,
    const float* __restrict__ bh, const float* __restrict__ Wfc,
    const float* __restrict__ bfc, float* __restrict__ out,
    u32* bar, bf16* hbuf) {
  const int tid = threadIdx.x;
  const int bid = blockIdx.x;
  const int wave = tid >> 6;
  const int lane = tid & 63;
  const int n = lane & 15;      // MFMA column / A-row selector
  const int quad = lane >> 4;   // k-chunk selector
  const int sub = n & 3;        // h-column within 4-group
  const int m0 = wave * 32;     // this wave's batch base (2 M-tiles)

  // Wh slice rows: local row r (0..31): gate=(r&15)>>2, hcol=bid*8+(r>>4)*4+(r&3)
  // pad +8 elems: row stride 520*2B -> 8B-aligned rows, benign bank rotation
  __shared__ bf16 lds_wh[32][520];
  __shared__ bf16 lds_wx[32][264];

  // stage Wh (f32 -> bf16): 32 rows x 512 cols, 4 elems per iteration
  for (int idx = tid; idx < 32 * 128; idx += 256) {
    int r = idx >> 7, c = (idx & 127) * 4;
    int R = ((r & 15) >> 2) * HID + bid * 8 + (r >> 4) * 4 + (r & 3);
    float4 v = *(const float4*)(Wh + R * HID + c);
    bf16x4 w; w[0] = (bf16)v.x; w[1] = (bf16)v.y; w[2] = (bf16)v.z; w[3] = (bf16)v.w;
    *(bf16x4*)(&lds_wh[r][c]) = w;
  }
  // stage Wx (f32 -> bf16): 32 rows x 256 cols
  for (int idx = tid; idx < 32 * 64; idx += 256) {
    int r = idx >> 6, c = (idx & 63) * 4;
    int R = ((r & 15) >> 2) * HID + bid * 8 + (r >> 4) * 4 + (r & 3);
    float4 v = *(const float4*)(Wx + R * DIM + c);
    bf16x4 w; w[0] = (bf16)v.x; w[1] = (bf16)v.y; w[2] = (bf16)v.z; w[3] = (bf16)v.w;
    *(bf16x4*)(&lds_wx[r][c]) = w;
  }

  // per-lane gate biases (bx+bh) for my two N-tiles
  int R0 = (n >> 2) * HID + bid * 8 + 0 * 4 + sub;
  int R1 = (n >> 2) * HID + bid * 8 + 1 * 4 + sub;
  float bias0 = bx[R0] + bh[R0];
  float bias1 = bx[R1] + bh[R1];

  __syncthreads();

  // cell state in f32 registers (meaningful on lanes n<4): [mt][nt][reg]
  float cst[2][2][4];
#pragma unroll
  for (int a = 0; a < 2; ++a)
#pragma unroll
    for (int b = 0; b < 2; ++b)
#pragma unroll
      for (int r = 0; r < 4; ++r) cst[a][b][r] = 0.f;

  u32* cnt = bar;
  u32* gen = bar + 1;
  const int srcf = (lane & 48) | (4 + sub);
  const int srcg = (lane & 48) | (8 + sub);
  const int srco = (lane & 48) | (12 + sub);

  const f32x4 b0v = {bias0, bias0, bias0, bias0};
  const f32x4 b1v = {bias1, bias1, bias1, bias1};

  for (int t = 0; t < T_STEPS; ++t) {
    const bf16* hrd = hbuf + (t & 1) * (BATCH * HID);
    bf16* hwr = hbuf + ((t + 1) & 1) * (BATCH * HID);

    f32x4 acc00 = b0v, acc01 = b1v, acc10 = b0v, acc11 = b1v;

    // ---- h @ Wh^T (K = 512), h stored bf16 in ws ----
    const bf16* h0p = hrd + (m0 + n) * HID + quad * 8;
    const bf16* h1p = h0p + 16 * HID;
#pragma unroll
    for (int k = 0; k < HID; k += 32) {
      bf16x8 A0 = *(const bf16x8*)(h0p + k);
      bf16x8 A1 = *(const bf16x8*)(h1p + k);
      bf16x8 B0 = *(const bf16x8*)(&lds_wh[n][quad * 8 + k]);
      bf16x8 B1 = *(const bf16x8*)(&lds_wh[16 + n][quad * 8 + k]);
      acc00 = mfma_bf16(A0, B0, acc00);
      acc01 = mfma_bf16(A0, B1, acc01);
      acc10 = mfma_bf16(A1, B0, acc10);
      acc11 = mfma_bf16(A1, B1, acc11);
    }
    // ---- x_t @ Wx^T (K = 256), f32 input converted on the fly ----
    const float* x0p = x + (size_t)((m0 + n) * 1024 + t) * DIM + quad * 8;
    const float* x1p = x0p + (size_t)16 * 1024 * DIM;
#pragma unroll
    for (int k = 0; k < DIM; k += 32) {
      bf16x8 A0 = cvt8(x0p + k);
      bf16x8 A1 = cvt8(x1p + k);
      bf16x8 B0 = *(const bf16x8*)(&lds_wx[n][quad * 8 + k]);
      bf16x8 B1 = *(const bf16x8*)(&lds_wx[16 + n][quad * 8 + k]);
      acc00 = mfma_bf16(A0, B0, acc00);
      acc01 = mfma_bf16(A0, B1, acc01);
      acc10 = mfma_bf16(A1, B0, acc10);
      acc11 = mfma_bf16(A1, B1, acc11);
    }

    // ---- gate nonlinearities + cell update ----
    // acc layout: col n = lane&15 (gate = n>>2, hcol-sub = n&3), row = quad*4 + r
    f32x4 accs[2][2] = {{acc00, acc01}, {acc10, acc11}};
#pragma unroll
    for (int mt = 0; mt < 2; ++mt) {
#pragma unroll
      for (int nt = 0; nt < 2; ++nt) {
#pragma unroll
        for (int r = 0; r < 4; ++r) {
          float v = accs[mt][nt][r];
          float s = fast_sigmoid(v);
          float th = fast_tanh(v);
          float pv = (n >= 8 && n < 12) ? th : s;  // g-gate lanes: tanh
          float fv = __shfl(pv, srcf, 64);
          float gv = __shfl(pv, srcg, 64);
          float ov = __shfl(pv, srco, 64);
          float cn = cst[mt][nt][r] * fv + pv * gv;  // pv == i on lanes n<4
          float hn = ov * fast_tanh(cn);
          cst[mt][nt][r] = cn;
          if (n < 4) {
            int m = m0 + mt * 16 + quad * 4 + r;
            int col = bid * 8 + nt * 4 + sub;
            hwr[m * HID + col] = (bf16)hn;
            if (t == T_STEPS - 1) out[m * HID + col] = hn;  // hT output, f32
          }
        }
      }
    }

    // ---- device-scope grid barrier ----
    __syncthreads();  // all waves of this block drained (vmcnt) before entering
    if (tid == 0) {
      __builtin_amdgcn_fence(__ATOMIC_RELEASE, "agent");  // L2 writeback (cross-XCD)
      u32 g = __hip_atomic_load(gen, __ATOMIC_RELAXED, __HIP_MEMORY_SCOPE_AGENT);
      u32 a = __hip_atomic_fetch_add(cnt, 1u, __ATOMIC_RELAXED, __HIP_MEMORY_SCOPE_AGENT);
      if (a == NB - 1) {
        __hip_atomic_store(cnt, 0u, __ATOMIC_RELAXED, __HIP_MEMORY_SCOPE_AGENT);
        __hip_atomic_fetch_add(gen, 1u, __ATOMIC_RELEASE, __HIP_MEMORY_SCOPE_AGENT);
      } else {
        while (__hip_atomic_load(gen, __ATOMIC_RELAXED, __HIP_MEMORY_SCOPE_AGENT) == g) {
          __builtin_amdgcn_s_sleep(2);
        }
      }
      __builtin_amdgcn_fence(__ATOMIC_ACQUIRE, "agent");  // invalidate L1/L2
    }
    __syncthreads();
  }

  // ---- final fc: out2[b][o] = hT @ Wfc^T + bfc (blocks 0..7, 16 cols each) ----
  if (bid < 8) {
    const bf16* hT = hbuf;  // t=1023 wrote buffer (1024 & 1) == 0
    float* out2 = out + BATCH * HID;
    int col = bid * 16 + n;
    float bv = bfc[col];
#pragma unroll
    for (int mt = 0; mt < 2; ++mt) {
      int mb = wave * 32 + mt * 16;
      f32x4 a4 = {bv, bv, bv, bv};
      const bf16* ar = hT + (mb + n) * HID + quad * 8;
      const float* br = Wfc + col * HID + quad * 8;
#pragma unroll
      for (int k = 0; k < HID; k += 32) {
        bf16x8 A = *(const bf16x8*)(ar + k);
        bf16x8 B = cvt8(br + k);
        a4 = mfma_bf16(A, B, a4);
      }
#pragma unroll
      for (int r = 0; r < 4; ++r) {
        out2[(mb + quad * 4 + r) * 128 + col] = a4[r];
      }
    }
  }
}

extern "C" void kernel_launch(void* const* d_in, const int* in_sizes, int n_in,
                              void* d_out, int out_size, void* d_ws, size_t ws_size,
                              hipStream_t stream) {
  (void)in_sizes; (void)n_in; (void)out_size; (void)ws_size;
  const float* x   = (const float*)d_in[0];
  const float* Wx  = (const float*)d_in[2];
  const float* bx  = (const float*)d_in[3];
  const float* Wh  = (const float*)d_in[4];
  const float* bh  = (const float*)d_in[5];
  const float* Wfc = (const float*)d_in[8];
  const float* bfc = (const float*)d_in[9];
  float* out = (float*)d_out;
  u32* bar = (u32*)d_ws;
  bf16* hbuf = (bf16*)((char*)d_ws + 128);

  // zero barrier state + both h buffers (h0 = 0); ws is re-poisoned each launch
  hipMemsetAsync(d_ws, 0, 128 + 2 * BATCH * HID * sizeof(bf16), stream);
  lstm_persist<<<dim3(NB), dim3(256), 0, stream>>>(x, Wx, bx, Wh, bh, Wfc, bfc,
                                                   out, bar, hbuf);
}